// Round 1
// baseline (612.078 us; speedup 1.0000x reference)
//
#include <hip/hip_runtime.h>
#include <math.h>

typedef _Float16 half_t;
typedef _Float16 half2_t __attribute__((ext_vector_type(2)));
typedef _Float16 half8_t __attribute__((ext_vector_type(8)));

#define T_ 64
#define B_ 256
#define D_ 16
#define S_ 64
#define SP_ 68   // padded y-history row stride (floats)
#define H_ 128
#define O_ 8
#define NSTEP 63
#define NT 512

// ws layout (halves): Wf3 [1024][128] | Wf1 [128][64] | Wf2 [128][128], row-major fp16
#define W3_OFF 0
#define W1_OFF 131072
#define W2_OFF 139264
#define WS_HALVES 155648

// DPP 16-lane butterfly add (VALU; validated R10/R11 of previous session)
#if __has_builtin(__builtin_amdgcn_mov_dpp)
#define DPP_ADD(x, ctrl) \
  ((x) + __int_as_float(__builtin_amdgcn_mov_dpp(__float_as_int(x), (ctrl), 0xF, 0xF, true)))
#else
#define DPP_ADD(x, ctrl) ((x) + __shfl_xor((x), (ctrl) == 0xB1 ? 1 : (ctrl) == 0x4E ? 2 : (ctrl) == 0x141 ? 4 : 8))
#endif

// AE[j] = coefficients on k[0..j] producing the NEXT stage input (j<5) or B_SOL (j==5)
__device__ constexpr float AE[6][6] = {
  {0.161f, 0.f, 0.f, 0.f, 0.f, 0.f},
  {-0.008480655492356989f, 0.335480655492357f, 0.f, 0.f, 0.f, 0.f},
  {2.8971530571054935f, -6.359448489975075f, 4.3622954328695815f, 0.f, 0.f, 0.f},
  {5.325864828439257f, -11.748883564062828f, 7.4955393428898365f, -0.09249506636175525f, 0.f, 0.f},
  {5.86145544294642f, -12.92096931784711f, 8.159367898576159f, -0.071584973281401f, -0.028269050394068383f, 0.f},
  {0.09646076681806523f, 0.01f, 0.4798896504144996f, 1.379008574103742f, -3.290069515436081f, 2.324710524099774f}
};
__device__ constexpr float CCn[6] = {0.f, 0.161f, 0.327f, 0.9f, 0.9800255409045097f, 1.f};

__device__ __forceinline__ float softplus_f(float x) {
  return fmaxf(x, 0.f) + __logf(1.f + __expf(-fabsf(x)));
}
__device__ __forceinline__ float tanh_f(float x) {
  float xc = fminf(fmaxf(x, -12.f), 12.f);
  float e = __expf(2.f * xc);
  return (e - 1.f) * __builtin_amdgcn_rcpf(e + 1.f);
}

// v_dot2_f32_f16: acc += a.x*b.x + a.y*b.y (f16 mul, f32 accumulate) — full-rate VALU
__device__ __forceinline__ float dot2f(half2_t a, half2_t b, float acc) {
  float af = __builtin_bit_cast(float, a);
  float bf = __builtin_bit_cast(float, b);
  asm("v_dot2_f32_f16 %0, %1, %2, %0" : "+v"(acc) : "v"(af), "v"(bf));
  return acc;
}

// ---------------- prologue: fp32 -> fp16 weight conversion (row-major) ----------------
__global__ __launch_bounds__(256) void convert_kernel(
    const float* __restrict__ Wf1, const float* __restrict__ Wf2,
    const float* __restrict__ Wf3, half_t* __restrict__ wsh)
{
  int q = blockIdx.x * 256 + threadIdx.x;
  if (q < W1_OFF) wsh[q] = (half_t)Wf3[q];
  else if (q < W2_OFF) wsh[q] = (half_t)Wf1[q - W1_OFF];
  else if (q < WS_HALVES) wsh[q] = (half_t)Wf2[q - W2_OFF];
}

// ---------------- main kernel ----------------
// 8 waves, 2/SIMD. All GEMVs on the VALU via v_dot2_f32_f16 (2 useful MACs/lane/instr
// = 64 MACs/cyc/SIMD vs MFMA-GEMV's 26). Weights register-resident per lane.
// Same 3-barrier phase skeleton and identical RK/butterfly epilogue as the MFMA version.
__global__ void __launch_bounds__(NT) __attribute__((amdgpu_waves_per_eu(2, 2)))
cde_kernel_dot2(
    const float* __restrict__ ts,
    const float* __restrict__ coeff_d,
    const float* __restrict__ coeff_c,
    const float* __restrict__ coeff_b,
    const float* __restrict__ coeff_a,
    const float* __restrict__ Wi1, const float* __restrict__ bi1,
    const float* __restrict__ Wi2, const float* __restrict__ bi2,
    const float* __restrict__ bf1, const float* __restrict__ bf2,
    const float* __restrict__ bf3,
    const float* __restrict__ Wr, const float* __restrict__ br,
    const half_t* __restrict__ wsh,
    float* __restrict__ out)
{
  __shared__ __align__(16) half_t syj_h[S_];
  __shared__ __align__(16) half_t sh1h[H_];
  __shared__ __align__(16) half_t sh2h[H_];
  __shared__ __align__(16) float shist[T_][SP_];   // y history (padded rows)
  __shared__ float sWr[O_ * S_];
  __shared__ float sbr[O_];
  __shared__ float sx0[D_];
  __shared__ float sini[H_];
  __shared__ float shs[T_];

  const int tid = threadIdx.x;
  const int b = blockIdx.x;
  const int w = tid >> 6;          // wave 0..7
  const int lane = tid & 63;
  const int q = lane >> 4;         // 16-lane row 0..3
  const int c = lane & 15;         // d-index / output column within row
  const int o1 = tid >> 2;         // h1/h2 output owned by this quad (0..127)
  const int kc1 = tid & 3;         // K-chunk within quad
  const int khalf = c & 1;         // K-half parity for GEMV3
  const int s0 = 8 * w + 2 * q;    // first y-row owned by this lane's 16-lane group

  const half_t* __restrict__ w3p = wsh + W3_OFF;
  const half_t* __restrict__ w1p = wsh + W1_OFF;
  const half_t* __restrict__ w2p = wsh + W2_OFF;

  // ---- persistent per-lane weight slices (VGPR-resident) ----
  // w1v: Wf1[o1][kc1*16 .. +15]   (8 half2)
  // w2v: Wf2[o1][kc1*32 .. +31]   (16 half2)
  // w3v[r]: K-half 'khalf' of Wf3 rows {16*s0+ce, 16*(s0+1)+ce, 16*s0+ce+1, 16*(s0+1)+ce+1}
  __align__(16) half2_t w1v[8], w2v[16], w3v[4][32];
  {
    const half8_t* p1 = (const half8_t*)(w1p + o1 * S_ + kc1 * 16);
    ((half8_t*)w1v)[0] = p1[0];
    ((half8_t*)w1v)[1] = p1[1];
    const half8_t* p2 = (const half8_t*)(w2p + o1 * H_ + kc1 * 32);
    #pragma unroll
    for (int i = 0; i < 4; ++i) ((half8_t*)w2v)[i] = p2[i];
    const int ce = c & 14;
    const int rows[4] = {16 * s0 + ce, 16 * (s0 + 1) + ce,
                         16 * s0 + ce + 1, 16 * (s0 + 1) + ce + 1};
    #pragma unroll
    for (int r = 0; r < 4; ++r) {
      const half8_t* p3 = (const half8_t*)(w3p + (size_t)rows[r] * H_ + khalf * 64);
      #pragma unroll
      for (int i = 0; i < 8; ++i) ((half8_t*)&w3v[r][0])[i] = p3[i];
    }
  }
  const float bf1v = bf1[o1];
  const float bf2v = bf2[o1];
  // epilogue rows this lane keeps: s0, s0+1 at column c = d
  const float bf3r0 = bf3[16 * s0 + c];
  const float bf3r1 = bf3[16 * (s0 + 1) + c];

  // ---- one-time staging + y0 ----
  if (tid < O_ * S_) sWr[tid] = Wr[tid];
  if (tid < O_) sbr[tid] = br[tid];
  if (tid < D_) sx0[tid] = coeff_a[(size_t)b * NSTEP * D_ + tid];
  if (tid < NSTEP) shs[tid] = ts[tid + 1] - ts[tid];
  __syncthreads();
  if (tid < H_) {
    float acc = bi1[tid];
    #pragma unroll
    for (int d = 0; d < D_; ++d) acc += sx0[d] * Wi1[tid * D_ + d];
    sini[tid] = softplus_f(acc);
  }
  __syncthreads();
  if (tid < S_) {
    float acc = bi2[tid];
    for (int h = 0; h < H_; ++h) acc += sini[h] * Wi2[tid * H_ + h];
    shist[0][tid] = acc;
  }
  __syncthreads();

  // RK state wave-uniform per 16-lane row: all lanes of row q track y[s0], y[s0+1]
  float yr0 = shist[0][s0];
  float yr1 = shist[0][s0 + 1];
  float kr0[6] = {0.f,0.f,0.f,0.f,0.f,0.f};
  float kr1[6] = {0.f,0.f,0.f,0.f,0.f,0.f};
  if (c == 0) {
    half2_t p; p[0] = (half_t)yr0; p[1] = (half_t)yr1;
    *(half2_t*)(syj_h + s0) = p;
  }
  __syncthreads();

  // ---- time loop ----
  for (int t = 0; t < NSTEP; ++t) {
    const float hstep = shs[t];
    const size_t cidx = ((size_t)b * NSTEP + t) * D_ + c;
    const float cbv = coeff_b[cidx];
    const float ccv = coeff_c[cidx];
    const float cdv = coeff_d[cidx];

    #pragma unroll
    for (int j = 0; j < 6; ++j) {
      // ---- h1: yj @ Wf1^T (K=64), 4 lanes/output, quad DPP reduce ----
      {
        __align__(16) half2_t y2v[8];
        const half8_t* yp = (const half8_t*)syj_h + kc1 * 2;
        ((half8_t*)y2v)[0] = yp[0];
        ((half8_t*)y2v)[1] = yp[1];
        float a0 = 0.f, a1 = 0.f;
        #pragma unroll
        for (int i = 0; i < 4; ++i) {
          a0 = dot2f(w1v[i], y2v[i], a0);
          a1 = dot2f(w1v[i + 4], y2v[i + 4], a1);
        }
        float v = a0 + a1;
        v = DPP_ADD(v, 0xB1);   // quad xor1
        v = DPP_ADD(v, 0x4E);   // quad xor2
        if (kc1 == 0) sh1h[o1] = (half_t)softplus_f(v + bf1v);
      }
      __syncthreads();   // B1

      // ---- h2: h1 @ Wf2^T (K=128), 4 lanes/output, quad DPP reduce ----
      {
        __align__(16) half2_t h1v[16];
        const half8_t* hp = (const half8_t*)sh1h + kc1 * 4;
        #pragma unroll
        for (int i = 0; i < 4; ++i) ((half8_t*)h1v)[i] = hp[i];
        float a0 = 0.f, a1 = 0.f;
        #pragma unroll
        for (int i = 0; i < 8; ++i) {
          a0 = dot2f(w2v[i], h1v[i], a0);
          a1 = dot2f(w2v[i + 8], h1v[i + 8], a1);
        }
        float v = a0 + a1;
        v = DPP_ADD(v, 0xB1);
        v = DPP_ADD(v, 0x4E);
        if (kc1 == 0) sh2h[o1] = (half_t)softplus_f(v + bf2v);
      }
      __syncthreads();   // B2

      // ---- GEMV3: 2 rows/lane, K split across lane pair (c, c^1) ----
      {
        __align__(16) half2_t h2v[32];   // this lane's K-half of h2
        const half8_t* hp = (const half8_t*)sh2h + khalf * 8;
        #pragma unroll
        for (int i = 0; i < 8; ++i) ((half8_t*)h2v)[i] = hp[i];

        float pa[4][2] = {{0.f,0.f},{0.f,0.f},{0.f,0.f},{0.f,0.f}};
        #pragma unroll
        for (int i = 0; i < 16; ++i) {
          #pragma unroll
          for (int r = 0; r < 4; ++r) {
            pa[r][0] = dot2f(w3v[r][2 * i],     h2v[2 * i],     pa[r][0]);
            pa[r][1] = dot2f(w3v[r][2 * i + 1], h2v[2 * i + 1], pa[r][1]);
          }
        }
        // recombine K-halves: partner lane (c^1) holds the other half of the SAME 4 rows
        float vf[4];
        #pragma unroll
        for (int r = 0; r < 4; ++r) {
          float s = pa[r][0] + pa[r][1];
          vf[r] = DPP_ADD(s, 0xB1);   // xor1: + partner's partial
        }
        // even c keeps rows {ce, ce} (= its own c), odd c keeps rows {ce+1} (= its own c)
        const float v0 = khalf ? vf[2] : vf[0];
        const float v1 = khalf ? vf[3] : vf[1];

        const float frac = CCn[j] * hstep;
        const float dx = cbv + frac * (2.f * ccv + 3.f * frac * cdv);
        float p0 = tanh_f(v0 + bf3r0) * dx;
        float p1 = tanh_f(v1 + bf3r1) * dx;
        // 16-lane butterfly via DPP (sums over d = c)
        p0 = DPP_ADD(p0, 0xB1);   p1 = DPP_ADD(p1, 0xB1);
        p0 = DPP_ADD(p0, 0x4E);   p1 = DPP_ADD(p1, 0x4E);
        p0 = DPP_ADD(p0, 0x141);  p1 = DPP_ADD(p1, 0x141);
        p0 = DPP_ADD(p0, 0x140);  p1 = DPP_ADD(p1, 0x140);

        // wave-uniform RK arithmetic
        kr0[j] = p0;
        kr1[j] = p1;
        float sa0 = AE[j][0] * kr0[0];
        float sa1 = AE[j][0] * kr1[0];
        #pragma unroll
        for (int m = 1; m < 6; ++m) if (m <= j) { sa0 = fmaf(AE[j][m], kr0[m], sa0); sa1 = fmaf(AE[j][m], kr1[m], sa1); }
        float yn0 = fmaf(hstep, sa0, yr0);
        float yn1 = fmaf(hstep, sa1, yr1);
        if (j == 5) { yr0 = yn0; yr1 = yn1; }
        if (c == 0) {
          half2_t p; p[0] = (half_t)yn0; p[1] = (half_t)yn1;
          *(half2_t*)(syj_h + s0) = p;
          if (j == 5) {
            float2 f; f.x = yn0; f.y = yn1;
            *(float2*)(&shist[t + 1][s0]) = f;
          }
        }
      }
      __syncthreads();   // B3
    }
  }

  // ---- batched projection epilogue: out[b, t, o] for all 64 t x 8 o ----
  __syncthreads();
  {
    const int tt = tid >> 3;       // 0..63
    const int oo = tid & 7;        // 0..7
    const float4* yp = (const float4*)(&shist[tt][0]);
    const float4* wp = (const float4*)(sWr + oo * S_);
    float a0 = 0.f, a1 = 0.f;
    #pragma unroll
    for (int i = 0; i < 16; i += 2) {
      float4 y0 = yp[i], w0 = wp[i];
      float4 y1 = yp[i + 1], w1 = wp[i + 1];
      a0 += y0.x * w0.x + y0.y * w0.y + y0.z * w0.z + y0.w * w0.w;
      a1 += y1.x * w1.x + y1.y * w1.y + y1.z * w1.z + y1.w * w1.w;
    }
    out[((size_t)b * T_ + tt) * O_ + oo] = a0 + a1 + sbr[oo];
  }
}

extern "C" void kernel_launch(void* const* d_in, const int* in_sizes, int n_in,
                              void* d_out, int out_size, void* d_ws, size_t ws_size,
                              hipStream_t stream) {
  const float* ts  = (const float*)d_in[0];
  const float* cd  = (const float*)d_in[1];
  const float* cc  = (const float*)d_in[2];
  const float* cb  = (const float*)d_in[3];
  const float* ca  = (const float*)d_in[4];
  const float* Wi1 = (const float*)d_in[5];
  const float* bi1 = (const float*)d_in[6];
  const float* Wi2 = (const float*)d_in[7];
  const float* bi2 = (const float*)d_in[8];
  const float* Wf1 = (const float*)d_in[9];
  const float* bf1 = (const float*)d_in[10];
  const float* Wf2 = (const float*)d_in[11];
  const float* bf2 = (const float*)d_in[12];
  const float* Wf3 = (const float*)d_in[13];
  const float* bf3 = (const float*)d_in[14];
  const float* Wr  = (const float*)d_in[15];
  const float* br  = (const float*)d_in[16];

  half_t* wsh = (half_t*)d_ws;
  hipLaunchKernelGGL(convert_kernel, dim3((WS_HALVES + 255) / 256), dim3(256), 0, stream,
                     Wf1, Wf2, Wf3, wsh);
  hipLaunchKernelGGL(cde_kernel_dot2, dim3(B_), dim3(NT), 0, stream,
                     ts, cd, cc, cb, ca, Wi1, bi1, Wi2, bi2,
                     bf1, bf2, bf3, Wr, br, wsh, (float*)d_out);
}

// Round 3
// 611.790 us; speedup vs baseline: 1.0005x; 1.0005x over previous
//
#include <hip/hip_runtime.h>
#include <math.h>

typedef _Float16 half_t;
typedef _Float16 half2_t __attribute__((ext_vector_type(2)));
typedef _Float16 half8_t __attribute__((ext_vector_type(8)));
typedef float float4_t __attribute__((ext_vector_type(4)));

#define T_ 64
#define B_ 256
#define D_ 16
#define S_ 64
#define SP_ 68   // padded y-history row stride (floats)
#define H_ 128
#define O_ 8
#define NSTEP 63
#define NT 512

// ws layout (halves): Wf3 [1024][128] | Wf1 [128][64] | Wf2 [128][128], row-major fp16
#define W3_OFF 0
#define W1_OFF 131072
#define W2_OFF 139264
#define WS_HALVES 155648

#define MFMA16(a, b, c) __builtin_amdgcn_mfma_f32_16x16x32_f16(a, b, c, 0, 0, 0)

// DPP 16-lane butterfly add (VALU; validated R10/R11)
#if __has_builtin(__builtin_amdgcn_mov_dpp)
#define DPP_ADD(x, ctrl) \
  ((x) + __int_as_float(__builtin_amdgcn_mov_dpp(__float_as_int(x), (ctrl), 0xF, 0xF, true)))
#else
#define DPP_ADD(x, ctrl) ((x) + __shfl_xor((x), (ctrl) == 0xB1 ? 1 : (ctrl) == 0x4E ? 2 : (ctrl) == 0x141 ? 4 : 8))
#endif

// AE[j] = coefficients on k[0..j] producing the NEXT stage input (j<5) or B_SOL (j==5)
__device__ constexpr float AE[6][6] = {
  {0.161f, 0.f, 0.f, 0.f, 0.f, 0.f},
  {-0.008480655492356989f, 0.335480655492357f, 0.f, 0.f, 0.f, 0.f},
  {2.8971530571054935f, -6.359448489975075f, 4.3622954328695815f, 0.f, 0.f, 0.f},
  {5.325864828439257f, -11.748883564062828f, 7.4955393428898365f, -0.09249506636175525f, 0.f, 0.f},
  {5.86145544294642f, -12.92096931784711f, 8.159367898576159f, -0.071584973281401f, -0.028269050394068383f, 0.f},
  {0.09646076681806523f, 0.01f, 0.4798896504144996f, 1.379008574103742f, -3.290069515436081f, 2.324710524099774f}
};
__device__ constexpr float CCn[6] = {0.f, 0.161f, 0.327f, 0.9f, 0.9800255409045097f, 1.f};

__device__ __forceinline__ float softplus_f(float x) {
  return fmaxf(x, 0.f) + __logf(1.f + __expf(-fabsf(x)));
}
__device__ __forceinline__ float tanh_f(float x) {
  float xc = fminf(fmaxf(x, -12.f), 12.f);
  float e = __expf(2.f * xc);
  return (e - 1.f) * __builtin_amdgcn_rcpf(e + 1.f);
}

// v_dot2_f32_f16: acc += a.x*b.x + a.y*b.y (f16 mul, f32 accumulate) — full-rate VALU
__device__ __forceinline__ float dot2f(half2_t a, half2_t b, float acc) {
  float af = __builtin_bit_cast(float, a);
  float bf = __builtin_bit_cast(float, b);
  asm("v_dot2_f32_f16 %0, %1, %2, %0" : "+v"(acc) : "v"(af), "v"(bf));
  return acc;
}

// ---------------- prologue: fp32 -> fp16 weight conversion (row-major) ----------------
__global__ __launch_bounds__(256) void convert_kernel(
    const float* __restrict__ Wf1, const float* __restrict__ Wf2,
    const float* __restrict__ Wf3, half_t* __restrict__ wsh)
{
  int q = blockIdx.x * 256 + threadIdx.x;
  if (q < W1_OFF) wsh[q] = (half_t)Wf3[q];
  else if (q < W2_OFF) wsh[q] = (half_t)Wf1[q - W1_OFF];
  else if (q < WS_HALVES) wsh[q] = (half_t)Wf2[q - W2_OFF];
}

// ---------------- main kernel ----------------
// 8 waves, 2/SIMD. Hybrid pipes: h1/h2 and K=0..63 of GEMV3 on MFMA (AGPR-resident
// weights); K=64..127 of GEMV3 on v_dot2_f32_f16 with per-lane weights chosen so each
// lane's dot2 partial lands on exactly its own epilogue outputs (no cross-lane merge).
// The dot2 chain is independent of the MFMA accumulators -> issues under MFMA latency.
__global__ void __launch_bounds__(NT) __attribute__((amdgpu_waves_per_eu(2, 2)))
cde_kernel_hybrid(
    const float* __restrict__ ts,
    const float* __restrict__ coeff_d,
    const float* __restrict__ coeff_c,
    const float* __restrict__ coeff_b,
    const float* __restrict__ coeff_a,
    const float* __restrict__ Wi1, const float* __restrict__ bi1,
    const float* __restrict__ Wi2, const float* __restrict__ bi2,
    const float* __restrict__ bf1, const float* __restrict__ bf2,
    const float* __restrict__ bf3,
    const float* __restrict__ Wr, const float* __restrict__ br,
    const half_t* __restrict__ wsh,
    float* __restrict__ out)
{
  __shared__ __align__(16) half_t syj_h[S_];
  __shared__ __align__(16) half_t sh1h[H_];
  __shared__ __align__(16) half_t sh2h[H_];
  __shared__ __align__(16) float shist[T_][SP_];   // y history (padded rows)
  __shared__ float sWr[O_ * S_];
  __shared__ float sbr[O_];
  __shared__ float sx0[D_];
  __shared__ float sini[H_];
  __shared__ float shs[T_];

  const int tid = threadIdx.x;
  const int b = blockIdx.x;
  const int w = tid >> 6;          // wave 0..7
  const int lane = tid & 63;
  const int q = lane >> 4;         // 16-lane row 0..3
  const int c = lane & 15;         // fragment column

  const half_t* __restrict__ w3p = wsh + W3_OFF;
  const half_t* __restrict__ w1p = wsh + W1_OFF;
  const half_t* __restrict__ w2p = wsh + W2_OFF;

  // ---- persistent B fragments (AGPR-resident; MFMA reads them natively) ----
  const int n1 = 16 * w + c;       // output column for h1/h2 tiles
  half8_t bW1[2], bW2[4], bW3[8][2];
  #pragma unroll
  for (int ks = 0; ks < 2; ++ks)
    bW1[ks] = *(const half8_t*)(w1p + n1 * S_ + ks * 32 + q * 8);
  #pragma unroll
  for (int ks = 0; ks < 4; ++ks)
    bW2[ks] = *(const half8_t*)(w2p + n1 * H_ + ks * 32 + q * 8);
  #pragma unroll
  for (int t = 0; t < 8; ++t) {
    const int r = 16 * (8 * w + t) + c;   // Wf3 row for this tile/col
    #pragma unroll
    for (int ks = 0; ks < 2; ++ks)        // MFMA covers K = 0..63 only
      bW3[t][ks] = *(const half8_t*)(w3p + (size_t)r * H_ + ks * 32 + q * 8);
  }
  const float bf1r = bf1[n1];
  const float bf2r = bf2[n1];
  // epilogue rows this lane keeps: s0 = 8w+2q, s1 = s0+1 (col c = d)
  const int s0 = 8 * w + 2 * q;
  const float bf3r0 = bf3[16 * s0 + c];
  const float bf3r1 = bf3[16 * (s0 + 1) + c];

  // ---- per-lane dot2 weights: FULL K tail 64..127 (32 half2) of both output rows ----
  half2_t w3q0[32], w3q1[32];
  {
    const half8_t* p0 = (const half8_t*)(w3p + (size_t)(16 * s0 + c) * H_ + 64);
    const half8_t* p1 = (const half8_t*)(w3p + (size_t)(16 * (s0 + 1) + c) * H_ + 64);
    #pragma unroll
    for (int i = 0; i < 8; ++i) {
      ((half8_t*)w3q0)[i] = p0[i];
      ((half8_t*)w3q1)[i] = p1[i];
    }
  }

  // ---- one-time staging + y0 ----
  if (tid < O_ * S_) sWr[tid] = Wr[tid];
  if (tid < O_) sbr[tid] = br[tid];
  if (tid < D_) sx0[tid] = coeff_a[(size_t)b * NSTEP * D_ + tid];
  if (tid < NSTEP) shs[tid] = ts[tid + 1] - ts[tid];
  __syncthreads();
  if (tid < H_) {
    float acc = bi1[tid];
    #pragma unroll
    for (int d = 0; d < D_; ++d) acc += sx0[d] * Wi1[tid * D_ + d];
    sini[tid] = softplus_f(acc);
  }
  __syncthreads();
  if (tid < S_) {
    float acc = bi2[tid];
    for (int h = 0; h < H_; ++h) acc += sini[h] * Wi2[tid * H_ + h];
    shist[0][tid] = acc;
  }
  __syncthreads();

  // RK state wave-uniform per 16-lane row: all lanes of row q track y[s0], y[s0+1]
  float yr0 = shist[0][s0];
  float yr1 = shist[0][s0 + 1];
  float kr0[6] = {0.f,0.f,0.f,0.f,0.f,0.f};
  float kr1[6] = {0.f,0.f,0.f,0.f,0.f,0.f};
  if (c == 0) {
    half2_t p; p[0] = (half_t)yr0; p[1] = (half_t)yr1;
    *(half2_t*)(syj_h + s0) = p;
  }
  __syncthreads();

  const float4_t Zv = {0.f, 0.f, 0.f, 0.f};

  // ---- time loop ----
  for (int t = 0; t < NSTEP; ++t) {
    const float hstep = shs[t];
    const size_t cidx = ((size_t)b * NSTEP + t) * D_ + c;
    const float cbv = coeff_b[cidx];
    const float ccv = coeff_c[cidx];
    const float cdv = coeff_d[cidx];
    // precompute dx for all 6 stages (off the epilogue critical chain)
    float dxj[6];
    #pragma unroll
    for (int j = 0; j < 6; ++j) {
      const float frac = CCn[j] * hstep;
      dxj[j] = cbv + frac * (2.f * ccv + 3.f * frac * cdv);
    }

    #pragma unroll
    for (int j = 0; j < 6; ++j) {
      // ---- h1: yj @ Wf1^T (K=64), split accumulators ----
      {
        const half8_t* ap = (const half8_t*)syj_h;
        half8_t a0 = ap[q];           // k = q*8 ..
        half8_t a1 = ap[4 + q];       // k = 32 + q*8 ..
        float4_t acc0 = MFMA16(a0, bW1[0], Zv);
        float4_t acc1 = MFMA16(a1, bW1[1], Zv);
        if (q == 0) sh1h[n1] = (half_t)softplus_f(acc0[0] + acc1[0] + bf1r);
      }
      __syncthreads();   // B1

      // ---- h2: h1 @ Wf2^T (K=128), two independent 2-chains ----
      {
        const half8_t* ap = (const half8_t*)sh1h;
        half8_t a0 = ap[q], a1 = ap[4 + q], a2 = ap[8 + q], a3 = ap[12 + q];
        float4_t accA = MFMA16(a0, bW2[0], Zv);
        float4_t accB = MFMA16(a1, bW2[1], Zv);
        accA = MFMA16(a2, bW2[2], accA);
        accB = MFMA16(a3, bW2[3], accB);
        if (q == 0) sh2h[n1] = (half_t)softplus_f(accA[0] + accB[0] + bf2r);
      }
      __syncthreads();   // B2

      // ---- GEMV3 hybrid: MFMA on K=0..63 (8 tiles x 2 slices) ∥ dot2 on K=64..127 ----
      {
        const half8_t* ap = (const half8_t*)sh2h;
        half8_t a0 = ap[q], a1 = ap[4 + q];
        float4_t acc3[8];
        #pragma unroll
        for (int tt = 0; tt < 8; ++tt) acc3[tt] = MFMA16(a0, bW3[tt][0], Zv);
        #pragma unroll
        for (int tt = 0; tt < 8; ++tt) acc3[tt] = MFMA16(a1, bW3[tt][1], acc3[tt]);

        // dot2 tail: K = 64..127 (all 32 half2), per-lane, lands directly on this
        // lane's outputs. Independent of the MFMA accumulators -> co-issues.
        half2_t h2t[32];
        {
          const half8_t* hp = (const half8_t*)sh2h + 8;   // halves 64..127 (broadcast)
          #pragma unroll
          for (int i = 0; i < 8; ++i) ((half8_t*)h2t)[i] = hp[i];
        }
        float d0 = 0.f, d1 = 0.f, d2 = 0.f, d3 = 0.f;
        #pragma unroll
        for (int i = 0; i < 16; ++i) {
          d0 = dot2f(w3q0[2 * i],     h2t[2 * i],     d0);
          d2 = dot2f(w3q0[2 * i + 1], h2t[2 * i + 1], d2);
          d1 = dot2f(w3q1[2 * i],     h2t[2 * i],     d1);
          d3 = dot2f(w3q1[2 * i + 1], h2t[2 * i + 1], d3);
        }

        // quad q consumes tiles 2q, 2q+1 (rows s0, s0+1 at col c)
        float v0, v1;
        if (q == 0)      { v0 = acc3[0][0]; v1 = acc3[1][0]; }
        else if (q == 1) { v0 = acc3[2][0]; v1 = acc3[3][0]; }
        else if (q == 2) { v0 = acc3[4][0]; v1 = acc3[5][0]; }
        else             { v0 = acc3[6][0]; v1 = acc3[7][0]; }
        v0 += d0 + d2;
        v1 += d1 + d3;

        const float dx = dxj[j];
        float p0 = tanh_f(v0 + bf3r0) * dx;
        float p1 = tanh_f(v1 + bf3r1) * dx;
        // 16-lane butterfly via DPP
        p0 = DPP_ADD(p0, 0xB1);   p1 = DPP_ADD(p1, 0xB1);
        p0 = DPP_ADD(p0, 0x4E);   p1 = DPP_ADD(p1, 0x4E);
        p0 = DPP_ADD(p0, 0x141);  p1 = DPP_ADD(p1, 0x141);
        p0 = DPP_ADD(p0, 0x140);  p1 = DPP_ADD(p1, 0x140);

        // wave-uniform RK arithmetic
        kr0[j] = p0;
        kr1[j] = p1;
        float sa0 = AE[j][0] * kr0[0];
        float sa1 = AE[j][0] * kr1[0];
        #pragma unroll
        for (int m = 1; m < 6; ++m) if (m <= j) { sa0 = fmaf(AE[j][m], kr0[m], sa0); sa1 = fmaf(AE[j][m], kr1[m], sa1); }
        float yn0 = fmaf(hstep, sa0, yr0);
        float yn1 = fmaf(hstep, sa1, yr1);
        if (j == 5) { yr0 = yn0; yr1 = yn1; }
        if (c == 0) {
          half2_t p; p[0] = (half_t)yn0; p[1] = (half_t)yn1;
          *(half2_t*)(syj_h + s0) = p;
          if (j == 5) {
            float2 f; f.x = yn0; f.y = yn1;
            *(float2*)(&shist[t + 1][s0]) = f;
          }
        }
      }
      __syncthreads();   // B3
    }
  }

  // ---- batched projection epilogue: out[b, t, o] for all 64 t x 8 o ----
  __syncthreads();
  {
    const int tt = tid >> 3;       // 0..63
    const int oo = tid & 7;        // 0..7
    const float4* yp = (const float4*)(&shist[tt][0]);
    const float4* wp = (const float4*)(sWr + oo * S_);
    float a0 = 0.f, a1 = 0.f;
    #pragma unroll
    for (int i = 0; i < 16; i += 2) {
      float4 y0 = yp[i], w0 = wp[i];
      float4 y1 = yp[i + 1], w1 = wp[i + 1];
      a0 += y0.x * w0.x + y0.y * w0.y + y0.z * w0.z + y0.w * w0.w;
      a1 += y1.x * w1.x + y1.y * w1.y + y1.z * w1.z + y1.w * w1.w;
    }
    out[((size_t)b * T_ + tt) * O_ + oo] = a0 + a1 + sbr[oo];
  }
}

extern "C" void kernel_launch(void* const* d_in, const int* in_sizes, int n_in,
                              void* d_out, int out_size, void* d_ws, size_t ws_size,
                              hipStream_t stream) {
  const float* ts  = (const float*)d_in[0];
  const float* cd  = (const float*)d_in[1];
  const float* cc  = (const float*)d_in[2];
  const float* cb  = (const float*)d_in[3];
  const float* ca  = (const float*)d_in[4];
  const float* Wi1 = (const float*)d_in[5];
  const float* bi1 = (const float*)d_in[6];
  const float* Wi2 = (const float*)d_in[7];
  const float* bi2 = (const float*)d_in[8];
  const float* Wf1 = (const float*)d_in[9];
  const float* bf1 = (const float*)d_in[10];
  const float* Wf2 = (const float*)d_in[11];
  const float* bf2 = (const float*)d_in[12];
  const float* Wf3 = (const float*)d_in[13];
  const float* bf3 = (const float*)d_in[14];
  const float* Wr  = (const float*)d_in[15];
  const float* br  = (const float*)d_in[16];

  half_t* wsh = (half_t*)d_ws;
  hipLaunchKernelGGL(convert_kernel, dim3((WS_HALVES + 255) / 256), dim3(256), 0, stream,
                     Wf1, Wf2, Wf3, wsh);
  hipLaunchKernelGGL(cde_kernel_hybrid, dim3(B_), dim3(NT), 0, stream,
                     ts, cd, cc, cb, ca, Wi1, bi1, Wi2, bi2,
                     bf1, bf2, bf3, Wr, br, wsh, (float*)d_out);
}

// Round 4
// 508.565 us; speedup vs baseline: 1.2035x; 1.2030x over previous
//
#include <hip/hip_runtime.h>
#include <math.h>

typedef _Float16 half_t;
typedef _Float16 half2_t __attribute__((ext_vector_type(2)));
typedef _Float16 half8_t __attribute__((ext_vector_type(8)));
typedef float float4_t __attribute__((ext_vector_type(4)));

#define T_ 64
#define B_ 256
#define D_ 16
#define S_ 64
#define SP_ 68   // padded y-history row stride (floats) to break projection bank conflicts
#define H_ 128
#define O_ 8
#define NSTEP 63
#define NT 512

// ws layout (halves): Wf3 [1024][128] | Wf1 [128][64] | Wf2 [128][128], row-major fp16
#define W3_OFF 0
#define W1_OFF 131072
#define W2_OFF 139264
#define WS_HALVES 155648

#define MFMA16(a, b, c) __builtin_amdgcn_mfma_f32_16x16x32_f16(a, b, c, 0, 0, 0)

// LDS-only barrier: wait ds ops, sync, fence compiler. Skips __syncthreads' vmcnt(0)
// drain (in-loop VMEM is lane-private coeff prefetch; no cross-lane visibility needed).
#define BAR_LDS() do { \
  asm volatile("s_waitcnt lgkmcnt(0)" ::: "memory"); \
  __builtin_amdgcn_s_barrier(); \
  asm volatile("" ::: "memory"); \
} while (0)

// DPP 16-lane butterfly add (VALU; validated R10/R11)
#if __has_builtin(__builtin_amdgcn_mov_dpp)
#define DPP_ADD(x, ctrl) \
  ((x) + __int_as_float(__builtin_amdgcn_mov_dpp(__float_as_int(x), (ctrl), 0xF, 0xF, true)))
#else
#define DPP_ADD(x, ctrl) ((x) + __shfl_xor((x), (ctrl) == 0xB1 ? 1 : (ctrl) == 0x4E ? 2 : (ctrl) == 0x141 ? 4 : 8))
#endif

// AE[j] = coefficients on k[0..j] producing the NEXT stage input (j<5) or B_SOL (j==5)
__device__ constexpr float AE[6][6] = {
  {0.161f, 0.f, 0.f, 0.f, 0.f, 0.f},
  {-0.008480655492356989f, 0.335480655492357f, 0.f, 0.f, 0.f, 0.f},
  {2.8971530571054935f, -6.359448489975075f, 4.3622954328695815f, 0.f, 0.f, 0.f},
  {5.325864828439257f, -11.748883564062828f, 7.4955393428898365f, -0.09249506636175525f, 0.f, 0.f},
  {5.86145544294642f, -12.92096931784711f, 8.159367898576159f, -0.071584973281401f, -0.028269050394068383f, 0.f},
  {0.09646076681806523f, 0.01f, 0.4798896504144996f, 1.379008574103742f, -3.290069515436081f, 2.324710524099774f}
};
__device__ constexpr float CCn[6] = {0.f, 0.161f, 0.327f, 0.9f, 0.9800255409045097f, 1.f};

__device__ __forceinline__ float softplus_f(float x) {
  return fmaxf(x, 0.f) + __logf(1.f + __expf(-fabsf(x)));
}
__device__ __forceinline__ float tanh_f(float x) {
  float xc = fminf(fmaxf(x, -12.f), 12.f);
  float e = __expf(2.f * xc);
  return (e - 1.f) * __builtin_amdgcn_rcpf(e + 1.f);
}

// ---------------- prologue: fp32 -> fp16 weight conversion (row-major) ----------------
__global__ __launch_bounds__(256) void convert_kernel(
    const float* __restrict__ Wf1, const float* __restrict__ Wf2,
    const float* __restrict__ Wf3, half_t* __restrict__ wsh)
{
  int q = blockIdx.x * 256 + threadIdx.x;
  if (q < W1_OFF) wsh[q] = (half_t)Wf3[q];
  else if (q < W2_OFF) wsh[q] = (half_t)Wf1[q - W1_OFF];
  else if (q < WS_HALVES) wsh[q] = (half_t)Wf2[q - W2_OFF];
}

// ---------------- main kernel ----------------
// R0 (458 us) structure: 8 waves, 2/SIMD, all weights AGPR-persistent. Per stage:
// [h1] B1 [h2] B2 [G3 + DPP + wave-uniform RK] B3. Changes vs R0:
//  (1) in-loop barriers are lgkmcnt-only (no vmcnt drain),
//  (2) coeff_b/c/d register-carried one t-iteration ahead (load latency off the
//      t-boundary critical path).
__global__ void __launch_bounds__(NT) __attribute__((amdgpu_waves_per_eu(2, 2)))
cde_kernel_mfma(
    const float* __restrict__ ts,
    const float* __restrict__ coeff_d,
    const float* __restrict__ coeff_c,
    const float* __restrict__ coeff_b,
    const float* __restrict__ coeff_a,
    const float* __restrict__ Wi1, const float* __restrict__ bi1,
    const float* __restrict__ Wi2, const float* __restrict__ bi2,
    const float* __restrict__ bf1, const float* __restrict__ bf2,
    const float* __restrict__ bf3,
    const float* __restrict__ Wr, const float* __restrict__ br,
    const half_t* __restrict__ wsh,
    float* __restrict__ out)
{
  __shared__ __align__(16) half_t syj_h[S_];
  __shared__ __align__(16) half_t sh1h[H_];
  __shared__ __align__(16) half_t sh2h[H_];
  __shared__ __align__(16) float shist[T_][SP_];   // y history (padded rows)
  __shared__ float sWr[O_ * S_];
  __shared__ float sbr[O_];
  __shared__ float sx0[D_];
  __shared__ float sini[H_];
  __shared__ float shs[T_];

  const int tid = threadIdx.x;
  const int b = blockIdx.x;
  const int w = tid >> 6;          // wave 0..7
  const int lane = tid & 63;
  const int q = lane >> 4;         // 16-lane row 0..3
  const int c = lane & 15;         // fragment column

  const half_t* __restrict__ w3p = wsh + W3_OFF;
  const half_t* __restrict__ w1p = wsh + W1_OFF;
  const half_t* __restrict__ w2p = wsh + W2_OFF;

  // ---- persistent B fragments (AGPR-resident; MFMA reads them natively) ----
  const int n1 = 16 * w + c;       // output column for h1/h2 tiles
  half8_t bW1[2], bW2[4], bW3[8][4];
  #pragma unroll
  for (int ks = 0; ks < 2; ++ks)
    bW1[ks] = *(const half8_t*)(w1p + n1 * S_ + ks * 32 + q * 8);
  #pragma unroll
  for (int ks = 0; ks < 4; ++ks)
    bW2[ks] = *(const half8_t*)(w2p + n1 * H_ + ks * 32 + q * 8);
  #pragma unroll
  for (int t = 0; t < 8; ++t) {
    const int r = 16 * (8 * w + t) + c;   // Wf3 row for this tile/col
    #pragma unroll
    for (int ks = 0; ks < 4; ++ks)
      bW3[t][ks] = *(const half8_t*)(w3p + (size_t)r * H_ + ks * 32 + q * 8);
  }
  const float bf1r = bf1[n1];
  const float bf2r = bf2[n1];
  // epilogue rows this lane keeps: s0 = 8w+2q, s1 = s0+1 (col c = d)
  const int s0 = 8 * w + 2 * q;
  const float bf3r0 = bf3[16 * s0 + c];
  const float bf3r1 = bf3[16 * (s0 + 1) + c];

  // ---- one-time staging + y0 ----
  if (tid < O_ * S_) sWr[tid] = Wr[tid];
  if (tid < O_) sbr[tid] = br[tid];
  if (tid < D_) sx0[tid] = coeff_a[(size_t)b * NSTEP * D_ + tid];
  if (tid < NSTEP) shs[tid] = ts[tid + 1] - ts[tid];
  __syncthreads();
  if (tid < H_) {
    float acc = bi1[tid];
    #pragma unroll
    for (int d = 0; d < D_; ++d) acc += sx0[d] * Wi1[tid * D_ + d];
    sini[tid] = softplus_f(acc);
  }
  __syncthreads();
  if (tid < S_) {
    float acc = bi2[tid];
    for (int h = 0; h < H_; ++h) acc += sini[h] * Wi2[tid * H_ + h];
    shist[0][tid] = acc;
  }
  __syncthreads();

  // RK state wave-uniform per 16-lane row: all lanes of row q track y[s0], y[s0+1]
  float yr0 = shist[0][s0];
  float yr1 = shist[0][s0 + 1];
  float kr0[6] = {0.f,0.f,0.f,0.f,0.f,0.f};
  float kr1[6] = {0.f,0.f,0.f,0.f,0.f,0.f};
  if (c == 0) {
    half2_t p; p[0] = (half_t)yr0; p[1] = (half_t)yr1;
    *(half2_t*)(syj_h + s0) = p;
  }
  __syncthreads();

  const float4_t Zv = {0.f, 0.f, 0.f, 0.f};

  // coeff register pipeline: values for step t live in (cbv,ccv,cdv); prefetch t+1
  const size_t cbase = (size_t)b * NSTEP * D_ + c;
  float cbv = coeff_b[cbase];
  float ccv = coeff_c[cbase];
  float cdv = coeff_d[cbase];

  // ---- time loop ----
  for (int t = 0; t < NSTEP; ++t) {
    // issue next step's coeff loads now; waits land at next iteration's dxj compute
    const int tn = (t + 1 < NSTEP) ? (t + 1) : t;
    const size_t cidxn = cbase + (size_t)tn * D_;
    const float cbn = coeff_b[cidxn];
    const float ccn = coeff_c[cidxn];
    const float cdn = coeff_d[cidxn];

    const float hstep = shs[t];
    // precompute dx for all 6 stages (off the epilogue critical chain)
    float dxj[6];
    #pragma unroll
    for (int j = 0; j < 6; ++j) {
      const float frac = CCn[j] * hstep;
      dxj[j] = cbv + frac * (2.f * ccv + 3.f * frac * cdv);
    }

    #pragma unroll
    for (int j = 0; j < 6; ++j) {
      // ---- h1: yj @ Wf1^T (K=64), split accumulators ----
      {
        const half8_t* ap = (const half8_t*)syj_h;
        half8_t a0 = ap[q];           // k = q*8 ..
        half8_t a1 = ap[4 + q];       // k = 32 + q*8 ..
        float4_t acc0 = MFMA16(a0, bW1[0], Zv);
        float4_t acc1 = MFMA16(a1, bW1[1], Zv);
        if (q == 0) sh1h[n1] = (half_t)softplus_f(acc0[0] + acc1[0] + bf1r);
      }
      BAR_LDS();   // B1

      // ---- h2: h1 @ Wf2^T (K=128), two independent 2-chains ----
      {
        const half8_t* ap = (const half8_t*)sh1h;
        half8_t a0 = ap[q], a1 = ap[4 + q], a2 = ap[8 + q], a3 = ap[12 + q];
        float4_t accA = MFMA16(a0, bW2[0], Zv);
        float4_t accB = MFMA16(a1, bW2[1], Zv);
        accA = MFMA16(a2, bW2[2], accA);
        accB = MFMA16(a3, bW2[3], accB);
        if (q == 0) sh2h[n1] = (half_t)softplus_f(accA[0] + accB[0] + bf2r);
      }
      BAR_LDS();   // B2

      // ---- GEMV3: 8 tiles (independent chains) + epilogue + RK ----
      {
        const half8_t* ap = (const half8_t*)sh2h;
        half8_t a0 = ap[q], a1 = ap[4 + q], a2 = ap[8 + q], a3 = ap[12 + q];
        float4_t acc3[8];
        #pragma unroll
        for (int tt = 0; tt < 8; ++tt) acc3[tt] = MFMA16(a0, bW3[tt][0], Zv);
        #pragma unroll
        for (int tt = 0; tt < 8; ++tt) acc3[tt] = MFMA16(a1, bW3[tt][1], acc3[tt]);
        #pragma unroll
        for (int tt = 0; tt < 8; ++tt) acc3[tt] = MFMA16(a2, bW3[tt][2], acc3[tt]);
        #pragma unroll
        for (int tt = 0; tt < 8; ++tt) acc3[tt] = MFMA16(a3, bW3[tt][3], acc3[tt]);

        // quad q consumes tiles 2q, 2q+1
        float v0, v1;
        if (q == 0)      { v0 = acc3[0][0]; v1 = acc3[1][0]; }
        else if (q == 1) { v0 = acc3[2][0]; v1 = acc3[3][0]; }
        else if (q == 2) { v0 = acc3[4][0]; v1 = acc3[5][0]; }
        else             { v0 = acc3[6][0]; v1 = acc3[7][0]; }

        const float dx = dxj[j];
        float p0 = tanh_f(v0 + bf3r0) * dx;
        float p1 = tanh_f(v1 + bf3r1) * dx;
        // 16-lane butterfly via DPP
        p0 = DPP_ADD(p0, 0xB1);   p1 = DPP_ADD(p1, 0xB1);
        p0 = DPP_ADD(p0, 0x4E);   p1 = DPP_ADD(p1, 0x4E);
        p0 = DPP_ADD(p0, 0x141);  p1 = DPP_ADD(p1, 0x141);
        p0 = DPP_ADD(p0, 0x140);  p1 = DPP_ADD(p1, 0x140);

        // wave-uniform RK arithmetic
        kr0[j] = p0;
        kr1[j] = p1;
        float sa0 = AE[j][0] * kr0[0];
        float sa1 = AE[j][0] * kr1[0];
        #pragma unroll
        for (int m = 1; m < 6; ++m) if (m <= j) { sa0 = fmaf(AE[j][m], kr0[m], sa0); sa1 = fmaf(AE[j][m], kr1[m], sa1); }
        float yn0 = fmaf(hstep, sa0, yr0);
        float yn1 = fmaf(hstep, sa1, yr1);
        if (j == 5) { yr0 = yn0; yr1 = yn1; }
        if (c == 0) {
          half2_t p; p[0] = (half_t)yn0; p[1] = (half_t)yn1;
          *(half2_t*)(syj_h + s0) = p;
          if (j == 5) {
            float2 f; f.x = yn0; f.y = yn1;
            *(float2*)(&shist[t + 1][s0]) = f;
          }
        }
      }
      BAR_LDS();   // B3
    }

    cbv = cbn; ccv = ccn; cdv = cdn;
  }

  // ---- batched projection epilogue: out[b, t, o] for all 64 t x 8 o ----
  __syncthreads();
  {
    const int tt = tid >> 3;       // 0..63
    const int oo = tid & 7;        // 0..7
    const float4* yp = (const float4*)(&shist[tt][0]);
    const float4* wp = (const float4*)(sWr + oo * S_);
    float a0 = 0.f, a1 = 0.f;
    #pragma unroll
    for (int i = 0; i < 16; i += 2) {
      float4 y0 = yp[i], w0 = wp[i];
      float4 y1 = yp[i + 1], w1 = wp[i + 1];
      a0 += y0.x * w0.x + y0.y * w0.y + y0.z * w0.z + y0.w * w0.w;
      a1 += y1.x * w1.x + y1.y * w1.y + y1.z * w1.z + y1.w * w1.w;
    }
    out[((size_t)b * T_ + tt) * O_ + oo] = a0 + a1 + sbr[oo];
  }
}

extern "C" void kernel_launch(void* const* d_in, const int* in_sizes, int n_in,
                              void* d_out, int out_size, void* d_ws, size_t ws_size,
                              hipStream_t stream) {
  const float* ts  = (const float*)d_in[0];
  const float* cd  = (const float*)d_in[1];
  const float* cc  = (const float*)d_in[2];
  const float* cb  = (const float*)d_in[3];
  const float* ca  = (const float*)d_in[4];
  const float* Wi1 = (const float*)d_in[5];
  const float* bi1 = (const float*)d_in[6];
  const float* Wi2 = (const float*)d_in[7];
  const float* bi2 = (const float*)d_in[8];
  const float* Wf1 = (const float*)d_in[9];
  const float* bf1 = (const float*)d_in[10];
  const float* Wf2 = (const float*)d_in[11];
  const float* bf2 = (const float*)d_in[12];
  const float* Wf3 = (const float*)d_in[13];
  const float* bf3 = (const float*)d_in[14];
  const float* Wr  = (const float*)d_in[15];
  const float* br  = (const float*)d_in[16];

  half_t* wsh = (half_t*)d_ws;
  hipLaunchKernelGGL(convert_kernel, dim3((WS_HALVES + 255) / 256), dim3(256), 0, stream,
                     Wf1, Wf2, Wf3, wsh);
  hipLaunchKernelGGL(cde_kernel_mfma, dim3(B_), dim3(NT), 0, stream,
                     ts, cd, cc, cb, ca, Wi1, bi1, Wi2, bi2,
                     bf1, bf2, bf3, Wr, br, wsh, (float*)d_out);
}

// Round 5
// 423.170 us; speedup vs baseline: 1.4464x; 1.2018x over previous
//
#include <hip/hip_runtime.h>
#include <math.h>

typedef _Float16 half_t;
typedef _Float16 half2_t __attribute__((ext_vector_type(2)));
typedef _Float16 half8_t __attribute__((ext_vector_type(8)));
typedef float float4_t __attribute__((ext_vector_type(4)));
typedef int int4v __attribute__((ext_vector_type(4)));

#define T_ 64
#define B_ 256
#define D_ 16
#define S_ 64
#define SP_ 68   // padded y-history row stride (floats)
#define H_ 128
#define O_ 8
#define NSTEP 63
#define NT 512

// ws layout (bytes):
//   [0, 131072)        Wf3 int8, row-major [1024][128]
//   [131072, 135168)   swf float[1024] per-row weight scales (max|row|/127)
//   [135168, 151552)   Wf1 fp16 [128][64]
//   [151552, 184320)   Wf2 fp16 [128][128]
#define W3I_OFF 0
#define SWF_OFF 131072
#define W1_OFF  135168
#define W2_OFF  151552

#define H2B 8.0f   // clamp bound for h2 int8 quantization (derived bound ~3)

#define MFMA16(a, b, c) __builtin_amdgcn_mfma_f32_16x16x32_f16(a, b, c, 0, 0, 0)
#define MFMAI8(a, b, c) __builtin_amdgcn_mfma_i32_16x16x64_i8(a, b, c, 0, 0, 0)

// LDS-only barrier (R4-validated): wait ds ops, sync, fence compiler.
#define BAR_LDS() do { \
  asm volatile("s_waitcnt lgkmcnt(0)" ::: "memory"); \
  __builtin_amdgcn_s_barrier(); \
  asm volatile("" ::: "memory"); \
} while (0)

// DPP 16-lane butterfly add (VALU; validated)
#if __has_builtin(__builtin_amdgcn_mov_dpp)
#define DPP_ADD(x, ctrl) \
  ((x) + __int_as_float(__builtin_amdgcn_mov_dpp(__float_as_int(x), (ctrl), 0xF, 0xF, true)))
#else
#define DPP_ADD(x, ctrl) ((x) + __shfl_xor((x), (ctrl) == 0xB1 ? 1 : (ctrl) == 0x4E ? 2 : (ctrl) == 0x141 ? 4 : 8))
#endif

// AE[j] = coefficients on k[0..j] producing the NEXT stage input (j<5) or B_SOL (j==5)
__device__ constexpr float AE[6][6] = {
  {0.161f, 0.f, 0.f, 0.f, 0.f, 0.f},
  {-0.008480655492356989f, 0.335480655492357f, 0.f, 0.f, 0.f, 0.f},
  {2.8971530571054935f, -6.359448489975075f, 4.3622954328695815f, 0.f, 0.f, 0.f},
  {5.325864828439257f, -11.748883564062828f, 7.4955393428898365f, -0.09249506636175525f, 0.f, 0.f},
  {5.86145544294642f, -12.92096931784711f, 8.159367898576159f, -0.071584973281401f, -0.028269050394068383f, 0.f},
  {0.09646076681806523f, 0.01f, 0.4798896504144996f, 1.379008574103742f, -3.290069515436081f, 2.324710524099774f}
};
__device__ constexpr float CCn[6] = {0.f, 0.161f, 0.327f, 0.9f, 0.9800255409045097f, 1.f};

__device__ __forceinline__ float softplus_f(float x) {
  return fmaxf(x, 0.f) + __logf(1.f + __expf(-fabsf(x)));
}
__device__ __forceinline__ float tanh_f(float x) {
  float xc = fminf(fmaxf(x, -12.f), 12.f);
  float e = __expf(2.f * xc);
  return (e - 1.f) * __builtin_amdgcn_rcpf(e + 1.f);
}

// ---------------- prologue 1: Wf1/Wf2 fp32 -> fp16 ----------------
__global__ __launch_bounds__(256) void convert12_kernel(
    const float* __restrict__ Wf1, const float* __restrict__ Wf2,
    unsigned char* __restrict__ wsb)
{
  half_t* w1h = (half_t*)(wsb + W1_OFF);
  half_t* w2h = (half_t*)(wsb + W2_OFF);
  int q = blockIdx.x * 256 + threadIdx.x;
  if (q < 8192) w1h[q] = (half_t)Wf1[q];
  else if (q < 24576) w2h[q - 8192] = (half_t)Wf2[q - 8192];
}

// ---------------- prologue 2: Wf3 fp32 -> int8 with per-row scale ----------------
// 256 blocks x 256 threads = 4 waves/block, one Wf3 row (128 elems) per wave.
__global__ __launch_bounds__(256) void convert3_kernel(
    const float* __restrict__ Wf3, unsigned char* __restrict__ wsb)
{
  signed char* w3i = (signed char*)(wsb + W3I_OFF);
  float* swf = (float*)(wsb + SWF_OFF);
  const int tid = threadIdx.x;
  const int wid = tid >> 6;
  const int lane = tid & 63;
  const int row = blockIdx.x * 4 + wid;
  const float a0 = Wf3[row * H_ + 2 * lane];
  const float a1 = Wf3[row * H_ + 2 * lane + 1];
  float m = fmaxf(fabsf(a0), fabsf(a1));
  #pragma unroll
  for (int s = 1; s < 64; s <<= 1) m = fmaxf(m, __shfl_xor(m, s));
  const float sw = fmaxf(m, 1e-20f) * (1.0f / 127.0f);
  const float inv = 1.0f / sw;
  w3i[row * H_ + 2 * lane]     = (signed char)(int)floorf(a0 * inv + 0.5f);
  w3i[row * H_ + 2 * lane + 1] = (signed char)(int)floorf(a1 * inv + 0.5f);
  if (lane == 0) swf[row] = sw;
}

// ---------------- main kernel ----------------
// R0/R4 structure (8 waves, 2/SIMD, weights register-persistent) with G3 on int8
// MFMA (K=64, 2x f16 rate): 16 i8-MFMA/wave vs 32 f16-MFMA -> G3 matrix time ~halved.
// h1/h2 stay fp16. h2 quantized to int8 (clamp 8, softplus>=0) with per-Wf3-row
// weight scales folded into the epilogue (v = int_acc * sw_row * (B/127)).
__global__ void __launch_bounds__(NT) __attribute__((amdgpu_waves_per_eu(2, 2)))
cde_kernel_i8(
    const float* __restrict__ ts,
    const float* __restrict__ coeff_d,
    const float* __restrict__ coeff_c,
    const float* __restrict__ coeff_b,
    const float* __restrict__ coeff_a,
    const float* __restrict__ Wi1, const float* __restrict__ bi1,
    const float* __restrict__ Wi2, const float* __restrict__ bi2,
    const float* __restrict__ bf1, const float* __restrict__ bf2,
    const float* __restrict__ bf3,
    const float* __restrict__ Wr, const float* __restrict__ br,
    const unsigned char* __restrict__ wsb,
    float* __restrict__ out)
{
  __shared__ __align__(16) half_t syj_h[S_];
  __shared__ __align__(16) half_t sh1h[H_];
  __shared__ __align__(16) unsigned char sh2b[H_];   // h2 quantized int8 (0..127)
  __shared__ __align__(16) float shist[T_][SP_];     // y history (padded rows)
  __shared__ float sWr[O_ * S_];
  __shared__ float sbr[O_];
  __shared__ float sx0[D_];
  __shared__ float sini[H_];
  __shared__ float shs[T_];

  const int tid = threadIdx.x;
  const int b = blockIdx.x;
  const int w = tid >> 6;          // wave 0..7
  const int lane = tid & 63;
  const int q = lane >> 4;         // 16-lane row 0..3
  const int c = lane & 15;         // fragment column

  const signed char* __restrict__ w3i = (const signed char*)(wsb + W3I_OFF);
  const float* __restrict__ swf = (const float*)(wsb + SWF_OFF);
  const half_t* __restrict__ w1p = (const half_t*)(wsb + W1_OFF);
  const half_t* __restrict__ w2p = (const half_t*)(wsb + W2_OFF);

  // ---- persistent B fragments ----
  const int n1 = 16 * w + c;       // output column for h1/h2 tiles
  half8_t bW1[2], bW2[4];
  int4v bW3i[8][2];
  #pragma unroll
  for (int ks = 0; ks < 2; ++ks)
    bW1[ks] = *(const half8_t*)(w1p + n1 * S_ + ks * 32 + q * 8);
  #pragma unroll
  for (int ks = 0; ks < 4; ++ks)
    bW2[ks] = *(const half8_t*)(w2p + n1 * H_ + ks * 32 + q * 8);
  #pragma unroll
  for (int t = 0; t < 8; ++t) {
    const int r = 16 * (8 * w + t) + c;   // Wf3 row for this tile/col
    #pragma unroll
    for (int ks = 0; ks < 2; ++ks)        // K=64 per i8 MFMA
      bW3i[t][ks] = *(const int4v*)(w3i + (size_t)r * H_ + ks * 64 + q * 16);
  }
  const float bf1r = bf1[n1];
  const float bf2r = bf2[n1];
  // epilogue rows this lane keeps: s0 = 8w+2q, s1 = s0+1 (col c = d)
  const int s0 = 8 * w + 2 * q;
  const float bf3r0 = bf3[16 * s0 + c];
  const float bf3r1 = bf3[16 * (s0 + 1) + c];
  // per-row weight scales folded with the activation scale (B/127)
  const float sw0s = swf[16 * s0 + c] * (H2B / 127.0f);
  const float sw1s = swf[16 * (s0 + 1) + c] * (H2B / 127.0f);

  // ---- one-time staging + y0 ----
  if (tid < O_ * S_) sWr[tid] = Wr[tid];
  if (tid < O_) sbr[tid] = br[tid];
  if (tid < D_) sx0[tid] = coeff_a[(size_t)b * NSTEP * D_ + tid];
  if (tid < NSTEP) shs[tid] = ts[tid + 1] - ts[tid];
  __syncthreads();
  if (tid < H_) {
    float acc = bi1[tid];
    #pragma unroll
    for (int d = 0; d < D_; ++d) acc += sx0[d] * Wi1[tid * D_ + d];
    sini[tid] = softplus_f(acc);
  }
  __syncthreads();
  if (tid < S_) {
    float acc = bi2[tid];
    for (int h = 0; h < H_; ++h) acc += sini[h] * Wi2[tid * H_ + h];
    shist[0][tid] = acc;
  }
  __syncthreads();

  // RK state wave-uniform per 16-lane row: all lanes of row q track y[s0], y[s0+1]
  float yr0 = shist[0][s0];
  float yr1 = shist[0][s0 + 1];
  float kr0[6] = {0.f,0.f,0.f,0.f,0.f,0.f};
  float kr1[6] = {0.f,0.f,0.f,0.f,0.f,0.f};
  if (c == 0) {
    half2_t p; p[0] = (half_t)yr0; p[1] = (half_t)yr1;
    *(half2_t*)(syj_h + s0) = p;
  }
  __syncthreads();

  const float4_t Zv = {0.f, 0.f, 0.f, 0.f};
  const int4v Zi = {0, 0, 0, 0};

  // coeff register pipeline (R4): values for step t in (cbv,ccv,cdv); prefetch t+1
  const size_t cbase = (size_t)b * NSTEP * D_ + c;
  float cbv = coeff_b[cbase];
  float ccv = coeff_c[cbase];
  float cdv = coeff_d[cbase];

  // ---- time loop ----
  for (int t = 0; t < NSTEP; ++t) {
    const int tn = (t + 1 < NSTEP) ? (t + 1) : t;
    const size_t cidxn = cbase + (size_t)tn * D_;
    const float cbn = coeff_b[cidxn];
    const float ccn = coeff_c[cidxn];
    const float cdn = coeff_d[cidxn];

    const float hstep = shs[t];
    float dxj[6];
    #pragma unroll
    for (int j = 0; j < 6; ++j) {
      const float frac = CCn[j] * hstep;
      dxj[j] = cbv + frac * (2.f * ccv + 3.f * frac * cdv);
    }

    #pragma unroll
    for (int j = 0; j < 6; ++j) {
      // ---- h1: yj @ Wf1^T (K=64), fp16 MFMA ----
      {
        const half8_t* ap = (const half8_t*)syj_h;
        half8_t a0 = ap[q];           // k = q*8 ..
        half8_t a1 = ap[4 + q];       // k = 32 + q*8 ..
        float4_t acc0 = MFMA16(a0, bW1[0], Zv);
        float4_t acc1 = MFMA16(a1, bW1[1], Zv);
        if (q == 0) sh1h[n1] = (half_t)softplus_f(acc0[0] + acc1[0] + bf1r);
      }
      BAR_LDS();   // B1

      // ---- h2: h1 @ Wf2^T (K=128), fp16 MFMA; output quantized to int8 ----
      {
        const half8_t* ap = (const half8_t*)sh1h;
        half8_t a0 = ap[q], a1 = ap[4 + q], a2 = ap[8 + q], a3 = ap[12 + q];
        float4_t accA = MFMA16(a0, bW2[0], Zv);
        float4_t accB = MFMA16(a1, bW2[1], Zv);
        accA = MFMA16(a2, bW2[2], accA);
        accB = MFMA16(a3, bW2[3], accB);
        if (q == 0) {
          const float h2v = softplus_f(accA[0] + accB[0] + bf2r);
          // softplus >= 0; clamp to H2B and round-to-nearest (x >= 0)
          const int qi = (int)(fminf(h2v, H2B) * (127.0f / H2B) + 0.5f);
          sh2b[n1] = (unsigned char)qi;
        }
      }
      BAR_LDS();   // B2

      // ---- GEMV3: int8 MFMA, 8 tiles x 2 K-slices ----
      {
        const int4v a0i = *(const int4v*)(sh2b + 16 * q);        // k = 0..63 slice
        const int4v a1i = *(const int4v*)(sh2b + 64 + 16 * q);   // k = 64..127 slice
        int4v iacc[8];
        #pragma unroll
        for (int tt = 0; tt < 8; ++tt) iacc[tt] = MFMAI8(a0i, bW3i[tt][0], Zi);
        #pragma unroll
        for (int tt = 0; tt < 8; ++tt) iacc[tt] = MFMAI8(a1i, bW3i[tt][1], iacc[tt]);

        // quad q consumes tiles 2q, 2q+1 (rows s0, s0+1 at col c)
        int i0, i1;
        if (q == 0)      { i0 = iacc[0][0]; i1 = iacc[1][0]; }
        else if (q == 1) { i0 = iacc[2][0]; i1 = iacc[3][0]; }
        else if (q == 2) { i0 = iacc[4][0]; i1 = iacc[5][0]; }
        else             { i0 = iacc[6][0]; i1 = iacc[7][0]; }
        const float v0 = (float)i0 * sw0s;
        const float v1 = (float)i1 * sw1s;

        const float dx = dxj[j];
        float p0 = tanh_f(v0 + bf3r0) * dx;
        float p1 = tanh_f(v1 + bf3r1) * dx;
        // 16-lane butterfly via DPP
        p0 = DPP_ADD(p0, 0xB1);   p1 = DPP_ADD(p1, 0xB1);
        p0 = DPP_ADD(p0, 0x4E);   p1 = DPP_ADD(p1, 0x4E);
        p0 = DPP_ADD(p0, 0x141);  p1 = DPP_ADD(p1, 0x141);
        p0 = DPP_ADD(p0, 0x140);  p1 = DPP_ADD(p1, 0x140);

        // wave-uniform RK arithmetic
        kr0[j] = p0;
        kr1[j] = p1;
        float sa0 = AE[j][0] * kr0[0];
        float sa1 = AE[j][0] * kr1[0];
        #pragma unroll
        for (int m = 1; m < 6; ++m) if (m <= j) { sa0 = fmaf(AE[j][m], kr0[m], sa0); sa1 = fmaf(AE[j][m], kr1[m], sa1); }
        float yn0 = fmaf(hstep, sa0, yr0);
        float yn1 = fmaf(hstep, sa1, yr1);
        if (j == 5) { yr0 = yn0; yr1 = yn1; }
        if (c == 0) {
          half2_t p; p[0] = (half_t)yn0; p[1] = (half_t)yn1;
          *(half2_t*)(syj_h + s0) = p;
          if (j == 5) {
            float2 f; f.x = yn0; f.y = yn1;
            *(float2*)(&shist[t + 1][s0]) = f;
          }
        }
      }
      BAR_LDS();   // B3
    }

    cbv = cbn; ccv = ccn; cdv = cdn;
  }

  // ---- batched projection epilogue: out[b, t, o] for all 64 t x 8 o ----
  __syncthreads();
  {
    const int tt = tid >> 3;       // 0..63
    const int oo = tid & 7;        // 0..7
    const float4* yp = (const float4*)(&shist[tt][0]);
    const float4* wp = (const float4*)(sWr + oo * S_);
    float a0 = 0.f, a1 = 0.f;
    #pragma unroll
    for (int i = 0; i < 16; i += 2) {
      float4 y0 = yp[i], w0 = wp[i];
      float4 y1 = yp[i + 1], w1 = wp[i + 1];
      a0 += y0.x * w0.x + y0.y * w0.y + y0.z * w0.z + y0.w * w0.w;
      a1 += y1.x * w1.x + y1.y * w1.y + y1.z * w1.z + y1.w * w1.w;
    }
    out[((size_t)b * T_ + tt) * O_ + oo] = a0 + a1 + sbr[oo];
  }
}

extern "C" void kernel_launch(void* const* d_in, const int* in_sizes, int n_in,
                              void* d_out, int out_size, void* d_ws, size_t ws_size,
                              hipStream_t stream) {
  const float* ts  = (const float*)d_in[0];
  const float* cd  = (const float*)d_in[1];
  const float* cc  = (const float*)d_in[2];
  const float* cb  = (const float*)d_in[3];
  const float* ca  = (const float*)d_in[4];
  const float* Wi1 = (const float*)d_in[5];
  const float* bi1 = (const float*)d_in[6];
  const float* Wi2 = (const float*)d_in[7];
  const float* bi2 = (const float*)d_in[8];
  const float* Wf1 = (const float*)d_in[9];
  const float* bf1 = (const float*)d_in[10];
  const float* Wf2 = (const float*)d_in[11];
  const float* bf2 = (const float*)d_in[12];
  const float* Wf3 = (const float*)d_in[13];
  const float* bf3 = (const float*)d_in[14];
  const float* Wr  = (const float*)d_in[15];
  const float* br  = (const float*)d_in[16];

  unsigned char* wsb = (unsigned char*)d_ws;
  hipLaunchKernelGGL(convert12_kernel, dim3(96), dim3(256), 0, stream, Wf1, Wf2, wsb);
  hipLaunchKernelGGL(convert3_kernel, dim3(256), dim3(256), 0, stream, Wf3, wsb);
  hipLaunchKernelGGL(cde_kernel_i8, dim3(B_), dim3(NT), 0, stream,
                     ts, cd, cc, cb, ca, Wi1, bi1, Wi2, bi2,
                     bf1, bf2, bf3, Wr, br, wsb, (float*)d_out);
}